// Round 10
// baseline (79.598 us; speedup 1.0000x reference)
//
#include <hip/hip_runtime.h>
#include <hip/hip_bf16.h>

#define NN   4096
#define INF_ 256
#define OUTF 64
#define NH   8
#define HSTR 72
#define NPAD 576   // 8 heads * 72 (64 g + 1 e + 7 zero pad)

using bf16x8 = __attribute__((ext_vector_type(8))) short;
using f32x4  = __attribute__((ext_vector_type(4))) float;
using i32x4  = __attribute__((ext_vector_type(4))) int;

__device__ __forceinline__ void gload_lds16(const void* g, void* l) {
  __builtin_amdgcn_global_load_lds((__attribute__((address_space(1))) void*)(g),
                                   (__attribute__((address_space(3))) void*)(l),
                                   16, 0, 0);
}

// compiler-invisible 16B global load (ext_vector output type — struct int4
// in an asm "=v" constraint was the round-9 abort). No auto-waitcnt is
// inserted for the results; WAITVM + SCHEDBAR are the manual guard.
__device__ __forceinline__ i32x4 gload_i4(const int* p) {
  i32x4 r;
  asm volatile("global_load_dwordx4 %0, %1, off" : "=v"(r) : "v"(p));
  return r;
}

__device__ __forceinline__ unsigned short f2bf(float x) {
  unsigned u = __float_as_uint(x);
  unsigned r = (u + 0x7FFFu + ((u >> 16) & 1u)) >> 16;
  return (unsigned short)r;
}

// ---------------- fused prologue: h = feat@W ; e = exp(h·a_dst) ; Gt build ----------------
__global__ __launch_bounds__(256) void k_prep(const float* __restrict__ feat,
                                              const float* __restrict__ W,
                                              const float* __restrict__ att,
                                              unsigned short* __restrict__ Gt) {
  __shared__ float fl[16][INF_];
  __shared__ float hl[16][65];
  __shared__ float el[NH][16];
  int j0 = blockIdx.x * 16;
  int tid = threadIdx.x;
  const float4* src = (const float4*)(feat + (size_t)j0 * INF_);
  for (int i = tid; i < 16 * 64; i += 256) {
    int r = i >> 6, c4 = i & 63;
    *(float4*)&fl[r][c4 * 4] = src[i];
  }
  __syncthreads();
  int c  = tid & 63;
  int rg = tid >> 6;
  float acc[4] = {0.f, 0.f, 0.f, 0.f};
#pragma unroll 8
  for (int k = 0; k < INF_; ++k) {
    float w = W[k * OUTF + c];
#pragma unroll
    for (int m = 0; m < 4; ++m) acc[m] = fmaf(fl[rg * 4 + m][k], w, acc[m]);
  }
#pragma unroll
  for (int m = 0; m < 4; ++m) hl[rg * 4 + m][c] = acc[m];
  __syncthreads();
  if (tid < NH * 16) {
    int hh = tid >> 4, row = tid & 15;
    float d = 0.f;
#pragma unroll 8
    for (int f = 0; f < 64; ++f) d = fmaf(hl[row][f], att[hh * 128 + 64 + f], d);
    el[hh][row] = expf(d);
  }
  __syncthreads();
  for (int i = tid; i < NPAD * 8; i += 256) {
    int u = i & 7, cc = i >> 3;
    int j2 = u * 2;
    int hh2 = cc / HSTR, c2 = cc - hh2 * HSTR;
    float e0 = el[hh2][j2], e1 = el[hh2][j2 + 1];
    float v0, v1;
    if (c2 < 64)      { v0 = e0 * hl[j2][c2]; v1 = e1 * hl[j2 + 1][c2]; }
    else if (c2 == 64){ v0 = e0;              v1 = e1; }
    else              { v0 = 0.f;             v1 = 0.f; }
    ushort2 o; o.x = f2bf(v0); o.y = f2bf(v1);
    *(ushort2*)&Gt[(size_t)cc * NN + j0 + j2] = o;
  }
}

// ---- Cp[ks] = adj(0/1) @ Gt^T ----
// A-fragments: asm global loads direct to registers in MFMA layout (no LDS
// round-trip, compiler-silent). B: global_load_lds, triple-buffered, staged
// 2 tiles ahead. One barrier/iter; lgkmcnt(0) before it (race fix).
#define BM 128
#define BN 96
#define BK 64
#define KS 4
#define NT 16                 // (NN/KS)/BK
#define NTILE 6               // 576/96
#define MTILE 32
#define BSZ (BN * BK)         // 6144 ushorts = 12 KB per B buffer

#define SEP()      asm volatile("" ::: "memory")
#define WAITVM(N)  asm volatile("s_waitcnt vmcnt(" #N ")" ::: "memory")
#define WAITLGKM() asm volatile("s_waitcnt lgkmcnt(0)" ::: "memory")
#define BAR()      asm volatile("s_barrier" ::: "memory")
#define SCHEDBAR() __builtin_amdgcn_sched_barrier(0)

__global__ __launch_bounds__(256, 3) void k_gemm(const int* __restrict__ adj,
                                                 const unsigned short* __restrict__ Bsrc,
                                                 float* __restrict__ Cp) {
  __shared__ alignas(16) unsigned short Bs[3 * BSZ];     // 36 KB total LDS

  // bijective XCD swizzle: nwg = 768 (%8==0); nt fastest -> the 6 blocks
  // sharing an A-row-band are adjacent (same XCD's L2).
  int id  = blockIdx.x;
  int wg  = (id & 7) * (768 >> 3) + (id >> 3);
  int nt  = wg % NTILE;
  int mt  = (wg / NTILE) % MTILE;
  int ks  = wg / (NTILE * MTILE);

  int m0 = mt * BM, n0 = nt * BN, k0 = ks * (NT * BK);
  int tid = threadIdx.x;
  int lane = tid & 63, wid = tid >> 6;     // 4 waves, all-M: wave rows wid*32..+31
  f32x4 acc[2][6] = {};

  int hi = lane >> 4, r15 = lane & 15, x7 = lane & 7;

  // A fragment pointers (per lane, MFMA A-layout for 16x16x32):
  // af[m][kk] elem j = adj[m0 + wid*32 + m*16 + r15][k0 + kt*64 + kk*32 + hi*8 + j]
  const int* A0 = adj + (size_t)(m0 + wid * 32 + r15) * NN + k0 + hi * 8;
  const int* A1 = A0 + (size_t)16 * NN;

  // B: global_load_lds with pre-swizzled source (3 chunks of 32 rows).
  int brow = tid >> 3, bgrp = tid & 7;
  const unsigned short* Bg = Bsrc + (size_t)(n0 + brow) * NN + k0
                           + (size_t)((bgrp ^ (brow & 7)) * 8);

  i32x4 ra[2][2][2];   // [m][kk][half] — all indices compile-time after unroll

#define ALOAD(KO)                                                             \
  do {                                                                        \
    ra[0][0][0] = gload_i4(A0 + (KO));                                        \
    ra[0][0][1] = gload_i4(A0 + (KO) + 4);                                    \
    ra[0][1][0] = gload_i4(A0 + (KO) + 32);                                   \
    ra[0][1][1] = gload_i4(A0 + (KO) + 36);                                   \
    ra[1][0][0] = gload_i4(A1 + (KO));                                        \
    ra[1][0][1] = gload_i4(A1 + (KO) + 4);                                    \
    ra[1][1][0] = gload_i4(A1 + (KO) + 32);                                   \
    ra[1][1][1] = gload_i4(A1 + (KO) + 36);                                   \
  } while (0)

#define CONVERT()                                                             \
  do { _Pragma("unroll") for (int m = 0; m < 2; ++m)                          \
       _Pragma("unroll") for (int kk = 0; kk < 2; ++kk) {                     \
    i32x4 p = ra[m][kk][0], q = ra[m][kk][1];                                 \
    union { uint4 u; bf16x8 v; } cv;                                          \
    cv.u.x = (unsigned)(p[0] | (p[1] << 16)) * 0x3F80u;                       \
    cv.u.y = (unsigned)(p[2] | (p[3] << 16)) * 0x3F80u;                       \
    cv.u.z = (unsigned)(q[0] | (q[1] << 16)) * 0x3F80u;                       \
    cv.u.w = (unsigned)(q[2] | (q[3] << 16)) * 0x3F80u;                       \
    af[m][kk] = cv.v;                                                         \
  } } while (0)

#define BSTAGE(BIO, KO)                                                       \
  do { _Pragma("unroll") for (int r = 0; r < 3; ++r)                          \
    gload_lds16(Bg + (size_t)(r * 32) * NN + (KO),                            \
                &Bs[(unsigned)(BIO) + (unsigned)((r * 32 + wid * 8) * BK)]);  \
  } while (0)

#define COMPUTE(BCO)                                                          \
  do { _Pragma("unroll") for (int kk = 0; kk < 2; ++kk) {                     \
    bf16x8 bfr[6];                                                            \
    _Pragma("unroll") for (int n = 0; n < 6; ++n)                             \
      bfr[n] = *(const bf16x8*)&Bs[(unsigned)(BCO) +                          \
                                   (unsigned)((n * 16 + r15) * BK)            \
                                   + (unsigned)(((kk * 4 + hi) ^ x7) * 8)];   \
    _Pragma("unroll") for (int m = 0; m < 2; ++m)                             \
      _Pragma("unroll") for (int n = 0; n < 6; ++n)                           \
        acc[m][n] = __builtin_amdgcn_mfma_f32_16x16x32_bf16(af[m][kk], bfr[n],\
                                                            acc[m][n], 0,0,0);\
  } } while (0)

  bf16x8 af[2][2];

  // prologue: B(0)->buf0, A(0)->ra, B(1)->buf1   (queue: B0=3, A0=8, B1=3)
  BSTAGE(0, 0); SEP();
  ALOAD(0);     SEP();
  BSTAGE(BSZ, BK);

#pragma unroll
  for (int kt = 0; kt < NT; ++kt) {
    // steady queue here: [B(kt)x3][A(kt)x8][B(kt+1)x3] -> vmcnt(3) lands
    // A(kt)+B(kt), keeps B(kt+1) in flight.
    if (kt < NT - 1) { WAITVM(3); } else { WAITVM(0); }
    SCHEDBAR();                    // rule #18: pin CONVERT after the wait
    CONVERT();                     // ra -> af (VALU); ra dead after this
    SCHEDBAR();                    // pin next ALOAD below (no ra overlap)
    if (kt + 1 < NT) { ALOAD((kt + 1) * BK); SEP(); }
    WAITLGKM();                    // own ds_reads retired (race fix)
    BAR();                         // all waves done reading buf((kt+2)%3)
    if (kt + 2 < NT) BSTAGE((unsigned)(((kt + 2) % 3) * BSZ), (kt + 2) * BK);
    COMPUTE((unsigned)((kt % 3) * BSZ));
  }

  float* Cout = Cp + (size_t)ks * NN * NPAD;
#pragma unroll
  for (int m = 0; m < 2; ++m)
#pragma unroll
    for (int n = 0; n < 6; ++n)
#pragma unroll
      for (int j = 0; j < 4; ++j) {
        int row = m0 + wid * 32 + m * 16 + hi * 4 + j;
        int col = n0 + n * 16 + r15;
        Cout[(size_t)row * NPAD + col] = acc[m][n][j];
      }
#undef ALOAD
#undef CONVERT
#undef BSTAGE
#undef COMPUTE
}

// ---------------- epilogue: out[i,f] = (1/8) sum_h num/den over KS partials ----------------
__global__ __launch_bounds__(256) void k_epi(const float* __restrict__ Cp,
                                             float* __restrict__ out) {
  int idx = blockIdx.x * 256 + threadIdx.x;
  int i = idx >> 6, f = idx & 63;
  const float* row = Cp + (size_t)i * NPAD;
  const size_t stride = (size_t)NN * NPAD;
  float s = 0.f;
#pragma unroll
  for (int hh = 0; hh < NH; ++hh) {
    float num = 0.f, den = 0.f;
#pragma unroll
    for (int ks = 0; ks < KS; ++ks) {
      num += row[ks * stride + hh * HSTR + f];
      den += row[ks * stride + hh * HSTR + 64];
    }
    float inv = (den > 0.f) ? (1.f / den) : 0.f;
    s = fmaf(num, inv, s);
  }
  out[idx] = 0.125f * s;
}

extern "C" void kernel_launch(void* const* d_in, const int* in_sizes, int n_in,
                              void* d_out, int out_size, void* d_ws, size_t ws_size,
                              hipStream_t stream) {
  const float* feat = (const float*)d_in[0];
  const int*   adj  = (const int*)d_in[1];
  const float* W    = (const float*)d_in[2];
  const float* att  = (const float*)d_in[3];
  float* out = (float*)d_out;

  const size_t GT_B = (size_t)NPAD * NN * 2;         // 4.5 MB
  char* ws = (char*)d_ws;
  unsigned short* Gt = (unsigned short*)(ws);
  float*          Cp = (float*)(ws + GT_B);          // KS x 9.4 MB partials

  k_prep<<<NN / 16, 256, 0, stream>>>(feat, W, att, Gt);
  k_gemm<<<NTILE * MTILE * KS, 256, 0, stream>>>(adj, Gt, Cp);
  k_epi <<<NN * OUTF / 256, 256, 0, stream>>>(Cp, out);
}

// Round 11
// 72.925 us; speedup vs baseline: 1.0915x; 1.0915x over previous
//
#include <hip/hip_runtime.h>
#include <hip/hip_bf16.h>

#define NN   4096
#define INF_ 256
#define OUTF 64
#define NH   8
#define HSTR 72
#define NPAD 576   // 8 heads * 72 (64 g + 1 e + 7 zero pad)

using bf16x8 = __attribute__((ext_vector_type(8))) short;
using f32x4  = __attribute__((ext_vector_type(4))) float;
using i32x2  = __attribute__((ext_vector_type(2))) int;
typedef unsigned long long ull;

__device__ __forceinline__ void gload_lds16(const void* g, void* l) {
  __builtin_amdgcn_global_load_lds((__attribute__((address_space(1))) void*)(g),
                                   (__attribute__((address_space(3))) void*)(l),
                                   16, 0, 0);
}

// compiler-invisible 8B global load (ext_vector output; no auto-waitcnt —
// WAITVM + SCHEDBAR are the manual guard, per round-10's validated pattern).
__device__ __forceinline__ i32x2 gload_i2(const void* p) {
  i32x2 r;
  asm volatile("global_load_dwordx2 %0, %1, off" : "=v"(r) : "v"(p));
  return r;
}

__device__ __forceinline__ unsigned short f2bf(float x) {
  unsigned u = __float_as_uint(x);
  unsigned r = (u + 0x7FFFu + ((u >> 16) & 1u)) >> 16;
  return (unsigned short)r;
}

// 8 adjacency bits -> 8 bf16 {0.0, 1.0} packed as 4 uint32.
// bit j even -> low half; (b&2)*0x1FC00000 == 0x3F800000 when bit1 set.
__device__ __forceinline__ bf16x8 expand8(unsigned b) {
  union { uint4 u; bf16x8 v; } cv;
  cv.u.x = ( b        & 1u) * 0x3F80u + ( b        & 2u) * 0x1FC00000u;
  cv.u.y = ((b >> 2)  & 1u) * 0x3F80u + ((b >> 2)  & 2u) * 0x1FC00000u;
  cv.u.z = ((b >> 4)  & 1u) * 0x3F80u + ((b >> 4)  & 2u) * 0x1FC00000u;
  cv.u.w = ((b >> 6)  & 1u) * 0x3F80u + ((b >> 6)  & 2u) * 0x1FC00000u;
  return cv.v;
}

// ---------------- bit-pack adjacency: 64 MB int32 -> 2 MB bits ----------------
// wave w handles row blockIdx.x*4+w; per chunk: 64 coalesced int32 -> __ballot
// -> one uint64. Bit i of word c = adj[row][c*64+i] > 0.
__global__ __launch_bounds__(256) void k_pack(const int* __restrict__ adj,
                                              ull* __restrict__ Abits) {
  int lane = threadIdx.x & 63, wave = threadIdx.x >> 6;
  int row  = blockIdx.x * 4 + wave;
  const int* src = adj + (size_t)row * NN;
  ull* dst = Abits + (size_t)row * (NN / 64);
#pragma unroll 4
  for (int c = 0; c < NN / 64; ++c) {
    int v = src[c * 64 + lane];
    ull m = __ballot(v > 0);
    if (lane == 0) dst[c] = m;
  }
}

// ---------------- fused prologue: h = feat@W ; e = exp(h·a_dst) ; Gt build ----------------
__global__ __launch_bounds__(256) void k_prep(const float* __restrict__ feat,
                                              const float* __restrict__ W,
                                              const float* __restrict__ att,
                                              unsigned short* __restrict__ Gt) {
  __shared__ float fl[16][INF_];
  __shared__ float hl[16][65];
  __shared__ float el[NH][16];
  int j0 = blockIdx.x * 16;
  int tid = threadIdx.x;
  const float4* src = (const float4*)(feat + (size_t)j0 * INF_);
  for (int i = tid; i < 16 * 64; i += 256) {
    int r = i >> 6, c4 = i & 63;
    *(float4*)&fl[r][c4 * 4] = src[i];
  }
  __syncthreads();
  int c  = tid & 63;
  int rg = tid >> 6;
  float acc[4] = {0.f, 0.f, 0.f, 0.f};
#pragma unroll 8
  for (int k = 0; k < INF_; ++k) {
    float w = W[k * OUTF + c];
#pragma unroll
    for (int m = 0; m < 4; ++m) acc[m] = fmaf(fl[rg * 4 + m][k], w, acc[m]);
  }
#pragma unroll
  for (int m = 0; m < 4; ++m) hl[rg * 4 + m][c] = acc[m];
  __syncthreads();
  if (tid < NH * 16) {
    int hh = tid >> 4, row = tid & 15;
    float d = 0.f;
#pragma unroll 8
    for (int f = 0; f < 64; ++f) d = fmaf(hl[row][f], att[hh * 128 + 64 + f], d);
    el[hh][row] = expf(d);
  }
  __syncthreads();
  for (int i = tid; i < NPAD * 8; i += 256) {
    int u = i & 7, cc = i >> 3;
    int j2 = u * 2;
    int hh2 = cc / HSTR, c2 = cc - hh2 * HSTR;
    float e0 = el[hh2][j2], e1 = el[hh2][j2 + 1];
    float v0, v1;
    if (c2 < 64)      { v0 = e0 * hl[j2][c2]; v1 = e1 * hl[j2 + 1][c2]; }
    else if (c2 == 64){ v0 = e0;              v1 = e1; }
    else              { v0 = 0.f;             v1 = 0.f; }
    ushort2 o; o.x = f2bf(v0); o.y = f2bf(v1);
    *(ushort2*)&Gt[(size_t)cc * NN + j0 + j2] = o;
  }
}

// ---- Cp[ks] = A(bit-packed 0/1, expanded in-reg) @ Gt^T ----
// Round-10's validated sync structure; A payload is now 2 loads x 8 B per
// iter per lane (A per XCD = 256 KB, B per XCD = 1.1 MB -> L2-resident).
#define BM 128
#define BN 96
#define BK 64
#define KS 4
#define NT 16                 // (NN/KS)/BK
#define NTILE 6               // 576/96
#define MTILE 32
#define BSZ (BN * BK)         // 6144 ushorts = 12 KB per B buffer

#define SEP()      asm volatile("" ::: "memory")
#define WAITVM(N)  asm volatile("s_waitcnt vmcnt(" #N ")" ::: "memory")
#define WAITLGKM() asm volatile("s_waitcnt lgkmcnt(0)" ::: "memory")
#define BAR()      asm volatile("s_barrier" ::: "memory")
#define SCHEDBAR() __builtin_amdgcn_sched_barrier(0)

__global__ __launch_bounds__(256, 3) void k_gemm(const ull* __restrict__ Abits,
                                                 const unsigned short* __restrict__ Bsrc,
                                                 float* __restrict__ Cp) {
  __shared__ alignas(16) unsigned short Bs[3 * BSZ];     // 36 KB total LDS

  // bijective XCD swizzle: nwg = 768 (%8==0); nt fastest.
  int id  = blockIdx.x;
  int wg  = (id & 7) * (768 >> 3) + (id >> 3);
  int nt  = wg % NTILE;
  int mt  = (wg / NTILE) % MTILE;
  int ks  = wg / (NTILE * MTILE);

  int m0 = mt * BM, n0 = nt * BN, k0 = ks * (NT * BK);
  int tid = threadIdx.x;
  int lane = tid & 63, wid = tid >> 6;     // 4 waves, all-M: wave rows wid*32..+31
  f32x4 acc[2][6] = {};

  int hi = lane >> 4, r15 = lane & 15, x7 = lane & 7;
  int sh8 = hi * 8;

  // A-bit pointers: one uint64 per row per K-tile (64 bits = BK columns).
  // af[m][kk] elem j = bit (hi*8+j) of word kk of Abits[row][k0/64 + kt].
  const ull* A0 = Abits + (size_t)(m0 + wid * 32 + r15) * (NN / 64) + (k0 >> 6);
  const ull* A1 = A0 + (size_t)16 * (NN / 64);

  // B: global_load_lds with pre-swizzled source (3 chunks of 32 rows).
  int brow = tid >> 3, bgrp = tid & 7;
  const unsigned short* Bg = Bsrc + (size_t)(n0 + brow) * NN + k0
                           + (size_t)((bgrp ^ (brow & 7)) * 8);

  i32x2 ra[2];        // [m] — lo word = kk0 bits, hi word = kk1 bits

#define ALOAD(KT)                                                             \
  do { ra[0] = gload_i2(A0 + (KT)); ra[1] = gload_i2(A1 + (KT)); } while (0)

#define CONVERT()                                                             \
  do { _Pragma("unroll") for (int m = 0; m < 2; ++m) {                        \
    unsigned w0 = (unsigned)ra[m][0], w1 = (unsigned)ra[m][1];                \
    af[m][0] = expand8((w0 >> sh8) & 0xFFu);                                  \
    af[m][1] = expand8((w1 >> sh8) & 0xFFu);                                  \
  } } while (0)

#define BSTAGE(BIO, KO)                                                       \
  do { _Pragma("unroll") for (int r = 0; r < 3; ++r)                          \
    gload_lds16(Bg + (size_t)(r * 32) * NN + (KO),                            \
                &Bs[(unsigned)(BIO) + (unsigned)((r * 32 + wid * 8) * BK)]);  \
  } while (0)

#define COMPUTE(BCO)                                                          \
  do { _Pragma("unroll") for (int kk = 0; kk < 2; ++kk) {                     \
    bf16x8 bfr[6];                                                            \
    _Pragma("unroll") for (int n = 0; n < 6; ++n)                             \
      bfr[n] = *(const bf16x8*)&Bs[(unsigned)(BCO) +                          \
                                   (unsigned)((n * 16 + r15) * BK)            \
                                   + (unsigned)(((kk * 4 + hi) ^ x7) * 8)];   \
    _Pragma("unroll") for (int m = 0; m < 2; ++m)                             \
      _Pragma("unroll") for (int n = 0; n < 6; ++n)                           \
        acc[m][n] = __builtin_amdgcn_mfma_f32_16x16x32_bf16(af[m][kk], bfr[n],\
                                                            acc[m][n], 0,0,0);\
  } } while (0)

  bf16x8 af[2][2];

  // prologue: B(0)->buf0, A(0)->ra, B(1)->buf1   (queue: B0=3, A0=2, B1=3)
  BSTAGE(0, 0); SEP();
  ALOAD(0);     SEP();
  BSTAGE(BSZ, BK);

#pragma unroll
  for (int kt = 0; kt < NT; ++kt) {
    // steady queue here: [B(kt)x3][A(kt)x2][B(kt+1)x3] -> vmcnt(3) lands
    // A(kt)+B(kt), keeps B(kt+1) in flight.
    if (kt < NT - 1) { WAITVM(3); } else { WAITVM(0); }
    SCHEDBAR();                    // rule #18: pin CONVERT after the wait
    CONVERT();                     // ra -> af (VALU); ra dead after this
    SCHEDBAR();                    // pin next ALOAD below (no ra overlap)
    if (kt + 1 < NT) { ALOAD(kt + 1); SEP(); }
    WAITLGKM();                    // own ds_reads retired (race fix)
    BAR();                         // all waves done reading buf((kt+2)%3)
    if (kt + 2 < NT) BSTAGE((unsigned)(((kt + 2) % 3) * BSZ), (kt + 2) * BK);
    COMPUTE((unsigned)((kt % 3) * BSZ));
  }

  float* Cout = Cp + (size_t)ks * NN * NPAD;
#pragma unroll
  for (int m = 0; m < 2; ++m)
#pragma unroll
    for (int n = 0; n < 6; ++n)
#pragma unroll
      for (int j = 0; j < 4; ++j) {
        int row = m0 + wid * 32 + m * 16 + hi * 4 + j;
        int col = n0 + n * 16 + r15;
        Cout[(size_t)row * NPAD + col] = acc[m][n][j];
      }
#undef ALOAD
#undef CONVERT
#undef BSTAGE
#undef COMPUTE
}

// ---------------- epilogue: out[i,f] = (1/8) sum_h num/den over KS partials ----------------
__global__ __launch_bounds__(256) void k_epi(const float* __restrict__ Cp,
                                             float* __restrict__ out) {
  int idx = blockIdx.x * 256 + threadIdx.x;
  int i = idx >> 6, f = idx & 63;
  const float* row = Cp + (size_t)i * NPAD;
  const size_t stride = (size_t)NN * NPAD;
  float s = 0.f;
#pragma unroll
  for (int hh = 0; hh < NH; ++hh) {
    float num = 0.f, den = 0.f;
#pragma unroll
    for (int ks = 0; ks < KS; ++ks) {
      num += row[ks * stride + hh * HSTR + f];
      den += row[ks * stride + hh * HSTR + 64];
    }
    float inv = (den > 0.f) ? (1.f / den) : 0.f;
    s = fmaf(num, inv, s);
  }
  out[idx] = 0.125f * s;
}

extern "C" void kernel_launch(void* const* d_in, const int* in_sizes, int n_in,
                              void* d_out, int out_size, void* d_ws, size_t ws_size,
                              hipStream_t stream) {
  const float* feat = (const float*)d_in[0];
  const int*   adj  = (const int*)d_in[1];
  const float* W    = (const float*)d_in[2];
  const float* att  = (const float*)d_in[3];
  float* out = (float*)d_out;

  const size_t GT_B = (size_t)NPAD * NN * 2;         // 4.5 MB
  const size_t AB_B = (size_t)NN * (NN / 64) * 8;    // 2 MB
  char* ws = (char*)d_ws;
  unsigned short* Gt    = (unsigned short*)(ws);
  ull*            Abits = (ull*)(ws + GT_B);
  float*          Cp    = (float*)(ws + GT_B + AB_B); // KS x 9.4 MB partials

  k_pack<<<NN / 4,  256, 0, stream>>>(adj, Abits);
  k_prep<<<NN / 16, 256, 0, stream>>>(feat, W, att, Gt);
  k_gemm<<<NTILE * MTILE * KS, 256, 0, stream>>>(Abits, Gt, Cp);
  k_epi <<<NN * OUTF / 256, 256, 0, stream>>>(Cp, out);
}

// Round 12
// 64.682 us; speedup vs baseline: 1.2306x; 1.1274x over previous
//
#include <hip/hip_runtime.h>
#include <hip/hip_bf16.h>

#define NN   4096
#define INF_ 256
#define OUTF 64
#define NH   8
#define HSTR 72
#define NPAD 576   // 8 heads * 72 (64 g + 1 e + 7 zero pad)

using bf16x8 = __attribute__((ext_vector_type(8))) short;
using f32x4  = __attribute__((ext_vector_type(4))) float;
using i32x2  = __attribute__((ext_vector_type(2))) int;
typedef unsigned long long ull;

__device__ __forceinline__ void gload_lds16(const void* g, void* l) {
  __builtin_amdgcn_global_load_lds((__attribute__((address_space(1))) void*)(g),
                                   (__attribute__((address_space(3))) void*)(l),
                                   16, 0, 0);
}

// compiler-invisible 8B global load (ext_vector output; no auto-waitcnt —
// WAITVM + SCHEDBAR are the manual guard, per round-10's validated pattern).
__device__ __forceinline__ i32x2 gload_i2(const void* p) {
  i32x2 r;
  asm volatile("global_load_dwordx2 %0, %1, off" : "=v"(r) : "v"(p));
  return r;
}

__device__ __forceinline__ unsigned short f2bf(float x) {
  unsigned u = __float_as_uint(x);
  unsigned r = (u + 0x7FFFu + ((u >> 16) & 1u)) >> 16;
  return (unsigned short)r;
}

// 8 adjacency bits -> 8 bf16 {0.0, 1.0} packed as 4 uint32.
__device__ __forceinline__ bf16x8 expand8(unsigned b) {
  union { uint4 u; bf16x8 v; } cv;
  cv.u.x = ( b        & 1u) * 0x3F80u + ( b        & 2u) * 0x1FC00000u;
  cv.u.y = ((b >> 2)  & 1u) * 0x3F80u + ((b >> 2)  & 2u) * 0x1FC00000u;
  cv.u.z = ((b >> 4)  & 1u) * 0x3F80u + ((b >> 4)  & 2u) * 0x1FC00000u;
  cv.u.w = ((b >> 6)  & 1u) * 0x3F80u + ((b >> 6)  & 2u) * 0x1FC00000u;
  return cv.v;
}

// ---------------- bit-pack adjacency: 64 MB int32 -> 2 MB bits ----------------
// Lane-local (no ballot, no serial chain): each thread owns 32 consecutive
// columns -> 8 independent int4 loads, one uint32 store. Bit j of word w =
// adj[w*32 + j] > 0 (little-endian pair == the GEMM's uint64 layout).
__global__ __launch_bounds__(256) void k_pack(const int* __restrict__ adj,
                                              unsigned* __restrict__ Abits32) {
  size_t t = (size_t)blockIdx.x * 256 + threadIdx.x;   // 524288 threads
  const int4* src = (const int4*)(adj + t * 32);
  int4 v[8];
#pragma unroll
  for (int i = 0; i < 8; ++i) v[i] = src[i];           // all 8 in flight
  unsigned m = 0;
#pragma unroll
  for (int i = 0; i < 8; ++i) {
    m |= (v[i].x > 0 ? 1u : 0u) << (4 * i);
    m |= (v[i].y > 0 ? 1u : 0u) << (4 * i + 1);
    m |= (v[i].z > 0 ? 1u : 0u) << (4 * i + 2);
    m |= (v[i].w > 0 ? 1u : 0u) << (4 * i + 3);
  }
  Abits32[t] = m;
}

// ---------------- fused prologue: h = feat@W ; e = exp(h·a_dst) ; Gt build ----------------
__global__ __launch_bounds__(256) void k_prep(const float* __restrict__ feat,
                                              const float* __restrict__ W,
                                              const float* __restrict__ att,
                                              unsigned short* __restrict__ Gt) {
  __shared__ float fl[16][INF_];
  __shared__ float hl[16][65];
  __shared__ float el[NH][16];
  int j0 = blockIdx.x * 16;
  int tid = threadIdx.x;
  const float4* src = (const float4*)(feat + (size_t)j0 * INF_);
  for (int i = tid; i < 16 * 64; i += 256) {
    int r = i >> 6, c4 = i & 63;
    *(float4*)&fl[r][c4 * 4] = src[i];
  }
  __syncthreads();
  int c  = tid & 63;
  int rg = tid >> 6;
  float acc[4] = {0.f, 0.f, 0.f, 0.f};
#pragma unroll 8
  for (int k = 0; k < INF_; ++k) {
    float w = W[k * OUTF + c];
#pragma unroll
    for (int m = 0; m < 4; ++m) acc[m] = fmaf(fl[rg * 4 + m][k], w, acc[m]);
  }
#pragma unroll
  for (int m = 0; m < 4; ++m) hl[rg * 4 + m][c] = acc[m];
  __syncthreads();
  if (tid < NH * 16) {
    int hh = tid >> 4, row = tid & 15;
    float d = 0.f;
#pragma unroll 8
    for (int f = 0; f < 64; ++f) d = fmaf(hl[row][f], att[hh * 128 + 64 + f], d);
    el[hh][row] = expf(d);
  }
  __syncthreads();
  for (int i = tid; i < NPAD * 8; i += 256) {
    int u = i & 7, cc = i >> 3;
    int j2 = u * 2;
    int hh2 = cc / HSTR, c2 = cc - hh2 * HSTR;
    float e0 = el[hh2][j2], e1 = el[hh2][j2 + 1];
    float v0, v1;
    if (c2 < 64)      { v0 = e0 * hl[j2][c2]; v1 = e1 * hl[j2 + 1][c2]; }
    else if (c2 == 64){ v0 = e0;              v1 = e1; }
    else              { v0 = 0.f;             v1 = 0.f; }
    ushort2 o; o.x = f2bf(v0); o.y = f2bf(v1);
    *(ushort2*)&Gt[(size_t)cc * NN + j0 + j2] = o;
  }
}

// ---- Cp[ks] = A(bit-packed 0/1, expanded in-reg) @ Gt^T ----
// Round-11's validated structure (passed twice), unchanged.
#define BM 128
#define BN 96
#define BK 64
#define KS 4
#define NT 16                 // (NN/KS)/BK
#define NTILE 6               // 576/96
#define MTILE 32
#define BSZ (BN * BK)         // 6144 ushorts = 12 KB per B buffer

#define SEP()      asm volatile("" ::: "memory")
#define WAITVM(N)  asm volatile("s_waitcnt vmcnt(" #N ")" ::: "memory")
#define WAITLGKM() asm volatile("s_waitcnt lgkmcnt(0)" ::: "memory")
#define BAR()      asm volatile("s_barrier" ::: "memory")
#define SCHEDBAR() __builtin_amdgcn_sched_barrier(0)

__global__ __launch_bounds__(256, 3) void k_gemm(const ull* __restrict__ Abits,
                                                 const unsigned short* __restrict__ Bsrc,
                                                 float* __restrict__ Cp) {
  __shared__ alignas(16) unsigned short Bs[3 * BSZ];     // 36 KB total LDS

  // bijective XCD swizzle: nwg = 768 (%8==0); nt fastest.
  int id  = blockIdx.x;
  int wg  = (id & 7) * (768 >> 3) + (id >> 3);
  int nt  = wg % NTILE;
  int mt  = (wg / NTILE) % MTILE;
  int ks  = wg / (NTILE * MTILE);

  int m0 = mt * BM, n0 = nt * BN, k0 = ks * (NT * BK);
  int tid = threadIdx.x;
  int lane = tid & 63, wid = tid >> 6;     // 4 waves, all-M: wave rows wid*32..+31
  f32x4 acc[2][6] = {};

  int hi = lane >> 4, r15 = lane & 15, x7 = lane & 7;
  int sh8 = hi * 8;

  // A-bit pointers: one uint64 per row per K-tile (64 bits = BK columns).
  const ull* A0 = Abits + (size_t)(m0 + wid * 32 + r15) * (NN / 64) + (k0 >> 6);
  const ull* A1 = A0 + (size_t)16 * (NN / 64);

  // B: global_load_lds with pre-swizzled source (3 chunks of 32 rows).
  int brow = tid >> 3, bgrp = tid & 7;
  const unsigned short* Bg = Bsrc + (size_t)(n0 + brow) * NN + k0
                           + (size_t)((bgrp ^ (brow & 7)) * 8);

  i32x2 ra[2];        // [m] — lo word = kk0 bits, hi word = kk1 bits

#define ALOAD(KT)                                                             \
  do { ra[0] = gload_i2(A0 + (KT)); ra[1] = gload_i2(A1 + (KT)); } while (0)

#define CONVERT()                                                             \
  do { _Pragma("unroll") for (int m = 0; m < 2; ++m) {                        \
    unsigned w0 = (unsigned)ra[m][0], w1 = (unsigned)ra[m][1];                \
    af[m][0] = expand8((w0 >> sh8) & 0xFFu);                                  \
    af[m][1] = expand8((w1 >> sh8) & 0xFFu);                                  \
  } } while (0)

#define BSTAGE(BIO, KO)                                                       \
  do { _Pragma("unroll") for (int r = 0; r < 3; ++r)                          \
    gload_lds16(Bg + (size_t)(r * 32) * NN + (KO),                            \
                &Bs[(unsigned)(BIO) + (unsigned)((r * 32 + wid * 8) * BK)]);  \
  } while (0)

#define COMPUTE(BCO)                                                          \
  do { _Pragma("unroll") for (int kk = 0; kk < 2; ++kk) {                     \
    bf16x8 bfr[6];                                                            \
    _Pragma("unroll") for (int n = 0; n < 6; ++n)                             \
      bfr[n] = *(const bf16x8*)&Bs[(unsigned)(BCO) +                          \
                                   (unsigned)((n * 16 + r15) * BK)            \
                                   + (unsigned)(((kk * 4 + hi) ^ x7) * 8)];   \
    _Pragma("unroll") for (int m = 0; m < 2; ++m)                             \
      _Pragma("unroll") for (int n = 0; n < 6; ++n)                           \
        acc[m][n] = __builtin_amdgcn_mfma_f32_16x16x32_bf16(af[m][kk], bfr[n],\
                                                            acc[m][n], 0,0,0);\
  } } while (0)

  bf16x8 af[2][2];

  // prologue: B(0)->buf0, A(0)->ra, B(1)->buf1   (queue: B0=3, A0=2, B1=3)
  BSTAGE(0, 0); SEP();
  ALOAD(0);     SEP();
  BSTAGE(BSZ, BK);

#pragma unroll
  for (int kt = 0; kt < NT; ++kt) {
    if (kt < NT - 1) { WAITVM(3); } else { WAITVM(0); }
    SCHEDBAR();                    // rule #18: pin CONVERT after the wait
    CONVERT();                     // ra -> af (VALU); ra dead after this
    SCHEDBAR();                    // pin next ALOAD below (no ra overlap)
    if (kt + 1 < NT) { ALOAD(kt + 1); SEP(); }
    WAITLGKM();                    // own ds_reads retired (race fix)
    BAR();                         // all waves done reading buf((kt+2)%3)
    if (kt + 2 < NT) BSTAGE((unsigned)(((kt + 2) % 3) * BSZ), (kt + 2) * BK);
    COMPUTE((unsigned)((kt % 3) * BSZ));
  }

  float* Cout = Cp + (size_t)ks * NN * NPAD;
#pragma unroll
  for (int m = 0; m < 2; ++m)
#pragma unroll
    for (int n = 0; n < 6; ++n)
#pragma unroll
      for (int j = 0; j < 4; ++j) {
        int row = m0 + wid * 32 + m * 16 + hi * 4 + j;
        int col = n0 + n * 16 + r15;
        Cout[(size_t)row * NPAD + col] = acc[m][n][j];
      }
#undef ALOAD
#undef CONVERT
#undef BSTAGE
#undef COMPUTE
}

// ---------------- epilogue: out[i,f] = (1/8) sum_h num/den over KS partials ----------------
__global__ __launch_bounds__(256) void k_epi(const float* __restrict__ Cp,
                                             float* __restrict__ out) {
  int idx = blockIdx.x * 256 + threadIdx.x;
  int i = idx >> 6, f = idx & 63;
  const float* row = Cp + (size_t)i * NPAD;
  const size_t stride = (size_t)NN * NPAD;
  float s = 0.f;
#pragma unroll
  for (int hh = 0; hh < NH; ++hh) {
    float num = 0.f, den = 0.f;
#pragma unroll
    for (int ks = 0; ks < KS; ++ks) {
      num += row[ks * stride + hh * HSTR + f];
      den += row[ks * stride + hh * HSTR + 64];
    }
    float inv = (den > 0.f) ? (1.f / den) : 0.f;
    s = fmaf(num, inv, s);
  }
  out[idx] = 0.125f * s;
}

extern "C" void kernel_launch(void* const* d_in, const int* in_sizes, int n_in,
                              void* d_out, int out_size, void* d_ws, size_t ws_size,
                              hipStream_t stream) {
  const float* feat = (const float*)d_in[0];
  const int*   adj  = (const int*)d_in[1];
  const float* W    = (const float*)d_in[2];
  const float* att  = (const float*)d_in[3];
  float* out = (float*)d_out;

  const size_t GT_B = (size_t)NPAD * NN * 2;         // 4.5 MB
  const size_t AB_B = (size_t)NN * (NN / 64) * 8;    // 2 MB
  char* ws = (char*)d_ws;
  unsigned short* Gt    = (unsigned short*)(ws);
  unsigned*       Ab32  = (unsigned*)(ws + GT_B);
  ull*            Abits = (ull*)(ws + GT_B);
  float*          Cp    = (float*)(ws + GT_B + AB_B); // KS x 9.4 MB partials

  k_pack<<<NN * NN / (32 * 256), 256, 0, stream>>>(adj, Ab32);
  k_prep<<<NN / 16, 256, 0, stream>>>(feat, W, att, Gt);
  k_gemm<<<NTILE * MTILE * KS, 256, 0, stream>>>(Abits, Gt, Cp);
  k_epi <<<NN * OUTF / 256, 256, 0, stream>>>(Cp, out);
}

// Round 13
// 61.552 us; speedup vs baseline: 1.2932x; 1.0509x over previous
//
#include <hip/hip_runtime.h>
#include <hip/hip_bf16.h>

#define NN   4096
#define INF_ 256
#define OUTF 64
#define NH   8
#define HSTR 72
#define NPAD 576   // 8 heads * 72 (64 g + 1 e + 7 zero pad)

using bf16x8 = __attribute__((ext_vector_type(8))) short;
using f32x4  = __attribute__((ext_vector_type(4))) float;
using i32x2  = __attribute__((ext_vector_type(2))) int;
typedef unsigned long long ull;

__device__ __forceinline__ void gload_lds16(const void* g, void* l) {
  __builtin_amdgcn_global_load_lds((__attribute__((address_space(1))) void*)(g),
                                   (__attribute__((address_space(3))) void*)(l),
                                   16, 0, 0);
}

// compiler-invisible 8B global load (round-10/11 validated pattern).
__device__ __forceinline__ i32x2 gload_i2(const void* p) {
  i32x2 r;
  asm volatile("global_load_dwordx2 %0, %1, off" : "=v"(r) : "v"(p));
  return r;
}

__device__ __forceinline__ unsigned short f2bf(float x) {
  unsigned u = __float_as_uint(x);
  unsigned r = (u + 0x7FFFu + ((u >> 16) & 1u)) >> 16;
  return (unsigned short)r;
}

// 8 adjacency bits -> 8 bf16 {0.0, 1.0} packed as 4 uint32.
__device__ __forceinline__ bf16x8 expand8(unsigned b) {
  union { uint4 u; bf16x8 v; } cv;
  cv.u.x = ( b        & 1u) * 0x3F80u + ( b        & 2u) * 0x1FC00000u;
  cv.u.y = ((b >> 2)  & 1u) * 0x3F80u + ((b >> 2)  & 2u) * 0x1FC00000u;
  cv.u.z = ((b >> 4)  & 1u) * 0x3F80u + ((b >> 4)  & 2u) * 0x1FC00000u;
  cv.u.w = ((b >> 6)  & 1u) * 0x3F80u + ((b >> 6)  & 2u) * 0x1FC00000u;
  return cv.v;
}

// ---------------- fused prologue: pack (blocks 0..2047) + prep (2048..2303) ----
// Independent work, one dispatch -> runs concurrently instead of serialized.
#define PACK_BLOCKS (NN * NN / (32 * 256))   // 2048
#define PREP_BLOCKS (NN / 16)                // 256

__global__ __launch_bounds__(256) void k_pp(const int* __restrict__ adj,
                                            unsigned* __restrict__ Abits32,
                                            const float* __restrict__ feat,
                                            const float* __restrict__ W,
                                            const float* __restrict__ att,
                                            unsigned short* __restrict__ Gt) {
  __shared__ float fl[16][INF_];
  __shared__ float hl[16][65];
  __shared__ float el[NH][16];
  int tid = threadIdx.x;

  if (blockIdx.x < PACK_BLOCKS) {
    // ---- bit-pack: lane-local, 8 independent int4 loads, 1 uint32 store.
    // Bit j of word w = adj[w*32+j] > 0 (LE pair == GEMM's uint64 layout).
    size_t t = (size_t)blockIdx.x * 256 + tid;
    const int4* src = (const int4*)(adj + t * 32);
    int4 v[8];
#pragma unroll
    for (int i = 0; i < 8; ++i) v[i] = src[i];
    unsigned m = 0;
#pragma unroll
    for (int i = 0; i < 8; ++i) {
      m |= (v[i].x > 0 ? 1u : 0u) << (4 * i);
      m |= (v[i].y > 0 ? 1u : 0u) << (4 * i + 1);
      m |= (v[i].z > 0 ? 1u : 0u) << (4 * i + 2);
      m |= (v[i].w > 0 ? 1u : 0u) << (4 * i + 3);
    }
    Abits32[t] = m;
    return;
  }

  // ---- prep: h = feat@W ; e = exp(h·a_dst) ; Gt build (16 rows/block)
  int j0 = (blockIdx.x - PACK_BLOCKS) * 16;
  const float4* src = (const float4*)(feat + (size_t)j0 * INF_);
  for (int i = tid; i < 16 * 64; i += 256) {
    int r = i >> 6, c4 = i & 63;
    *(float4*)&fl[r][c4 * 4] = src[i];
  }
  __syncthreads();
  int c  = tid & 63;
  int rg = tid >> 6;
  float acc[4] = {0.f, 0.f, 0.f, 0.f};
#pragma unroll 8
  for (int k = 0; k < INF_; ++k) {
    float w = W[k * OUTF + c];
#pragma unroll
    for (int m = 0; m < 4; ++m) acc[m] = fmaf(fl[rg * 4 + m][k], w, acc[m]);
  }
#pragma unroll
  for (int m = 0; m < 4; ++m) hl[rg * 4 + m][c] = acc[m];
  __syncthreads();
  if (tid < NH * 16) {
    int hh = tid >> 4, row = tid & 15;
    float d = 0.f;
#pragma unroll 8
    for (int f = 0; f < 64; ++f) d = fmaf(hl[row][f], att[hh * 128 + 64 + f], d);
    el[hh][row] = expf(d);
  }
  __syncthreads();
  for (int i = tid; i < NPAD * 8; i += 256) {
    int u = i & 7, cc = i >> 3;
    int j2 = u * 2;
    int hh2 = cc / HSTR, c2 = cc - hh2 * HSTR;
    float e0 = el[hh2][j2], e1 = el[hh2][j2 + 1];
    float v0, v1;
    if (c2 < 64)      { v0 = e0 * hl[j2][c2]; v1 = e1 * hl[j2 + 1][c2]; }
    else if (c2 == 64){ v0 = e0;              v1 = e1; }
    else              { v0 = 0.f;             v1 = 0.f; }
    ushort2 o; o.x = f2bf(v0); o.y = f2bf(v1);
    *(ushort2*)&Gt[(size_t)cc * NN + j0 + j2] = o;
  }
}

// ---- Cp[ks] = A(bit-packed 0/1, expanded in-reg) @ Gt^T ----
// Round-11/12's validated structure (passed 2x), unchanged.
#define BM 128
#define BN 96
#define BK 64
#define KS 4
#define NT 16                 // (NN/KS)/BK
#define NTILE 6               // 576/96
#define MTILE 32
#define BSZ (BN * BK)         // 6144 ushorts = 12 KB per B buffer

#define SEP()      asm volatile("" ::: "memory")
#define WAITVM(N)  asm volatile("s_waitcnt vmcnt(" #N ")" ::: "memory")
#define WAITLGKM() asm volatile("s_waitcnt lgkmcnt(0)" ::: "memory")
#define BAR()      asm volatile("s_barrier" ::: "memory")
#define SCHEDBAR() __builtin_amdgcn_sched_barrier(0)

__global__ __launch_bounds__(256, 3) void k_gemm(const ull* __restrict__ Abits,
                                                 const unsigned short* __restrict__ Bsrc,
                                                 float* __restrict__ Cp) {
  __shared__ alignas(16) unsigned short Bs[3 * BSZ];     // 36 KB total LDS

  // bijective XCD swizzle: nwg = 768 (%8==0); nt fastest.
  int id  = blockIdx.x;
  int wg  = (id & 7) * (768 >> 3) + (id >> 3);
  int nt  = wg % NTILE;
  int mt  = (wg / NTILE) % MTILE;
  int ks  = wg / (NTILE * MTILE);

  int m0 = mt * BM, n0 = nt * BN, k0 = ks * (NT * BK);
  int tid = threadIdx.x;
  int lane = tid & 63, wid = tid >> 6;     // 4 waves, all-M: wave rows wid*32..+31
  f32x4 acc[2][6] = {};

  int hi = lane >> 4, r15 = lane & 15, x7 = lane & 7;
  int sh8 = hi * 8;

  // A-bit pointers: one uint64 per row per K-tile (64 bits = BK columns).
  const ull* A0 = Abits + (size_t)(m0 + wid * 32 + r15) * (NN / 64) + (k0 >> 6);
  const ull* A1 = A0 + (size_t)16 * (NN / 64);

  // B: global_load_lds with pre-swizzled source (3 chunks of 32 rows).
  int brow = tid >> 3, bgrp = tid & 7;
  const unsigned short* Bg = Bsrc + (size_t)(n0 + brow) * NN + k0
                           + (size_t)((bgrp ^ (brow & 7)) * 8);

  i32x2 ra[2];        // [m] — lo word = kk0 bits, hi word = kk1 bits

#define ALOAD(KT)                                                             \
  do { ra[0] = gload_i2(A0 + (KT)); ra[1] = gload_i2(A1 + (KT)); } while (0)

#define CONVERT()                                                             \
  do { _Pragma("unroll") for (int m = 0; m < 2; ++m) {                        \
    unsigned w0 = (unsigned)ra[m][0], w1 = (unsigned)ra[m][1];                \
    af[m][0] = expand8((w0 >> sh8) & 0xFFu);                                  \
    af[m][1] = expand8((w1 >> sh8) & 0xFFu);                                  \
  } } while (0)

#define BSTAGE(BIO, KO)                                                       \
  do { _Pragma("unroll") for (int r = 0; r < 3; ++r)                          \
    gload_lds16(Bg + (size_t)(r * 32) * NN + (KO),                            \
                &Bs[(unsigned)(BIO) + (unsigned)((r * 32 + wid * 8) * BK)]);  \
  } while (0)

#define COMPUTE(BCO)                                                          \
  do { _Pragma("unroll") for (int kk = 0; kk < 2; ++kk) {                     \
    bf16x8 bfr[6];                                                            \
    _Pragma("unroll") for (int n = 0; n < 6; ++n)                             \
      bfr[n] = *(const bf16x8*)&Bs[(unsigned)(BCO) +                          \
                                   (unsigned)((n * 16 + r15) * BK)            \
                                   + (unsigned)(((kk * 4 + hi) ^ x7) * 8)];   \
    _Pragma("unroll") for (int m = 0; m < 2; ++m)                             \
      _Pragma("unroll") for (int n = 0; n < 6; ++n)                           \
        acc[m][n] = __builtin_amdgcn_mfma_f32_16x16x32_bf16(af[m][kk], bfr[n],\
                                                            acc[m][n], 0,0,0);\
  } } while (0)

  bf16x8 af[2][2];

  // prologue: B(0)->buf0, A(0)->ra, B(1)->buf1   (queue: B0=3, A0=2, B1=3)
  BSTAGE(0, 0); SEP();
  ALOAD(0);     SEP();
  BSTAGE(BSZ, BK);

#pragma unroll
  for (int kt = 0; kt < NT; ++kt) {
    if (kt < NT - 1) { WAITVM(3); } else { WAITVM(0); }
    SCHEDBAR();                    // rule #18: pin CONVERT after the wait
    CONVERT();                     // ra -> af (VALU); ra dead after this
    SCHEDBAR();                    // pin next ALOAD below (no ra overlap)
    if (kt + 1 < NT) { ALOAD(kt + 1); SEP(); }
    WAITLGKM();                    // own ds_reads retired (race fix)
    BAR();                         // all waves done reading buf((kt+2)%3)
    if (kt + 2 < NT) BSTAGE((unsigned)(((kt + 2) % 3) * BSZ), (kt + 2) * BK);
    COMPUTE((unsigned)((kt % 3) * BSZ));
  }

  float* Cout = Cp + (size_t)ks * NN * NPAD;
#pragma unroll
  for (int m = 0; m < 2; ++m)
#pragma unroll
    for (int n = 0; n < 6; ++n)
#pragma unroll
      for (int j = 0; j < 4; ++j) {
        int row = m0 + wid * 32 + m * 16 + hi * 4 + j;
        int col = n0 + n * 16 + r15;
        Cout[(size_t)row * NPAD + col] = acc[m][n][j];
      }
#undef ALOAD
#undef CONVERT
#undef BSTAGE
#undef COMPUTE
}

// ---------------- epilogue: out[i,f] = (1/8) sum_h num/den over KS partials ----------------
__global__ __launch_bounds__(256) void k_epi(const float* __restrict__ Cp,
                                             float* __restrict__ out) {
  int idx = blockIdx.x * 256 + threadIdx.x;
  int i = idx >> 6, f = idx & 63;
  const float* row = Cp + (size_t)i * NPAD;
  const size_t stride = (size_t)NN * NPAD;
  float s = 0.f;
#pragma unroll
  for (int hh = 0; hh < NH; ++hh) {
    float num = 0.f, den = 0.f;
#pragma unroll
    for (int ks = 0; ks < KS; ++ks) {
      num += row[ks * stride + hh * HSTR + f];
      den += row[ks * stride + hh * HSTR + 64];
    }
    float inv = (den > 0.f) ? (1.f / den) : 0.f;
    s = fmaf(num, inv, s);
  }
  out[idx] = 0.125f * s;
}

extern "C" void kernel_launch(void* const* d_in, const int* in_sizes, int n_in,
                              void* d_out, int out_size, void* d_ws, size_t ws_size,
                              hipStream_t stream) {
  const float* feat = (const float*)d_in[0];
  const int*   adj  = (const int*)d_in[1];
  const float* W    = (const float*)d_in[2];
  const float* att  = (const float*)d_in[3];
  float* out = (float*)d_out;

  const size_t GT_B = (size_t)NPAD * NN * 2;         // 4.5 MB
  const size_t AB_B = (size_t)NN * (NN / 64) * 8;    // 2 MB
  char* ws = (char*)d_ws;
  unsigned short* Gt    = (unsigned short*)(ws);
  unsigned*       Ab32  = (unsigned*)(ws + GT_B);
  ull*            Abits = (ull*)(ws + GT_B);
  float*          Cp    = (float*)(ws + GT_B + AB_B); // KS x 9.4 MB partials

  k_pp  <<<PACK_BLOCKS + PREP_BLOCKS, 256, 0, stream>>>(adj, Ab32, feat, W, att, Gt);
  k_gemm<<<NTILE * MTILE * KS, 256, 0, stream>>>(Abits, Gt, Cp);
  k_epi <<<NN * OUTF / 256, 256, 0, stream>>>(Cp, out);
}

// Round 14
// 59.662 us; speedup vs baseline: 1.3342x; 1.0317x over previous
//
#include <hip/hip_runtime.h>
#include <hip/hip_bf16.h>

#define NN   4096
#define INF_ 256
#define OUTF 64
#define NH   8
#define HSTR 72
#define NPAD 576   // 8 heads * 72 (64 g + 1 e + 7 zero pad)

using bf16x8 = __attribute__((ext_vector_type(8))) short;
using f32x4  = __attribute__((ext_vector_type(4))) float;
using i32x2  = __attribute__((ext_vector_type(2))) int;
typedef unsigned long long ull;

__device__ __forceinline__ void gload_lds16(const void* g, void* l) {
  __builtin_amdgcn_global_load_lds((__attribute__((address_space(1))) void*)(g),
                                   (__attribute__((address_space(3))) void*)(l),
                                   16, 0, 0);
}

// compiler-invisible 8B global load (round-10/11 validated pattern).
__device__ __forceinline__ i32x2 gload_i2(const void* p) {
  i32x2 r;
  asm volatile("global_load_dwordx2 %0, %1, off" : "=v"(r) : "v"(p));
  return r;
}

__device__ __forceinline__ unsigned short f2bf(float x) {
  unsigned u = __float_as_uint(x);
  unsigned r = (u + 0x7FFFu + ((u >> 16) & 1u)) >> 16;
  return (unsigned short)r;
}

// 8 adjacency bits -> 8 bf16 {0.0, 1.0} packed as 4 uint32.
__device__ __forceinline__ bf16x8 expand8(unsigned b) {
  union { uint4 u; bf16x8 v; } cv;
  cv.u.x = ( b        & 1u) * 0x3F80u + ( b        & 2u) * 0x1FC00000u;
  cv.u.y = ((b >> 2)  & 1u) * 0x3F80u + ((b >> 2)  & 2u) * 0x1FC00000u;
  cv.u.z = ((b >> 4)  & 1u) * 0x3F80u + ((b >> 4)  & 2u) * 0x1FC00000u;
  cv.u.w = ((b >> 6)  & 1u) * 0x3F80u + ((b >> 6)  & 2u) * 0x1FC00000u;
  return cv.v;
}

// ---------------- fused prologue: prep (blocks 0..255) + pack (256..2303) ----
// Prep blocks FIRST so every CU gets one latency-bound prep block immediately,
// with BW-bound pack blocks alongside (round-13 had pack first -> prep blocks
// only started as pack drained -> still serialized; this is the fix).
#define PREP_BLOCKS (NN / 16)                // 256
#define PACK_BLOCKS (NN * NN / (32 * 256))   // 2048

__global__ __launch_bounds__(256) void k_pp(const int* __restrict__ adj,
                                            unsigned* __restrict__ Abits32,
                                            const float* __restrict__ feat,
                                            const float* __restrict__ W,
                                            const float* __restrict__ att,
                                            unsigned short* __restrict__ Gt) {
  __shared__ float fl[16][INF_];
  __shared__ float hl[16][65];
  __shared__ float el[NH][16];
  int tid = threadIdx.x;

  if (blockIdx.x >= PREP_BLOCKS) {
    // ---- bit-pack: lane-local, 8 independent int4 loads, 1 uint32 store.
    // Bit j of word w = adj[w*32+j] > 0 (LE pair == GEMM's uint64 layout).
    size_t t = (size_t)(blockIdx.x - PREP_BLOCKS) * 256 + tid;
    const int4* src = (const int4*)(adj + t * 32);
    int4 v[8];
#pragma unroll
    for (int i = 0; i < 8; ++i) v[i] = src[i];
    unsigned m = 0;
#pragma unroll
    for (int i = 0; i < 8; ++i) {
      m |= (v[i].x > 0 ? 1u : 0u) << (4 * i);
      m |= (v[i].y > 0 ? 1u : 0u) << (4 * i + 1);
      m |= (v[i].z > 0 ? 1u : 0u) << (4 * i + 2);
      m |= (v[i].w > 0 ? 1u : 0u) << (4 * i + 3);
    }
    Abits32[t] = m;
    return;
  }

  // ---- prep: h = feat@W ; e = exp(h·a_dst) ; Gt build (16 rows/block)
  int j0 = blockIdx.x * 16;
  const float4* src = (const float4*)(feat + (size_t)j0 * INF_);
  for (int i = tid; i < 16 * 64; i += 256) {
    int r = i >> 6, c4 = i & 63;
    *(float4*)&fl[r][c4 * 4] = src[i];
  }
  __syncthreads();
  int c  = tid & 63;
  int rg = tid >> 6;
  float acc[4] = {0.f, 0.f, 0.f, 0.f};
#pragma unroll 8
  for (int k = 0; k < INF_; ++k) {
    float w = W[k * OUTF + c];
#pragma unroll
    for (int m = 0; m < 4; ++m) acc[m] = fmaf(fl[rg * 4 + m][k], w, acc[m]);
  }
#pragma unroll
  for (int m = 0; m < 4; ++m) hl[rg * 4 + m][c] = acc[m];
  __syncthreads();
  if (tid < NH * 16) {
    int hh = tid >> 4, row = tid & 15;
    float d = 0.f;
#pragma unroll 8
    for (int f = 0; f < 64; ++f) d = fmaf(hl[row][f], att[hh * 128 + 64 + f], d);
    el[hh][row] = expf(d);
  }
  __syncthreads();
  for (int i = tid; i < NPAD * 8; i += 256) {
    int u = i & 7, cc = i >> 3;
    int j2 = u * 2;
    int hh2 = cc / HSTR, c2 = cc - hh2 * HSTR;
    float e0 = el[hh2][j2], e1 = el[hh2][j2 + 1];
    float v0, v1;
    if (c2 < 64)      { v0 = e0 * hl[j2][c2]; v1 = e1 * hl[j2 + 1][c2]; }
    else if (c2 == 64){ v0 = e0;              v1 = e1; }
    else              { v0 = 0.f;             v1 = 0.f; }
    ushort2 o; o.x = f2bf(v0); o.y = f2bf(v1);
    *(ushort2*)&Gt[(size_t)cc * NN + j0 + j2] = o;
  }
}

// ---- Cp[ks] = A(bit-packed 0/1, expanded in-reg) @ Gt^T ----
// Round-11/12/13's validated structure (passed 3x), unchanged.
#define BM 128
#define BN 96
#define BK 64
#define KS 4
#define NT 16                 // (NN/KS)/BK
#define NTILE 6               // 576/96
#define MTILE 32
#define BSZ (BN * BK)         // 6144 ushorts = 12 KB per B buffer

#define SEP()      asm volatile("" ::: "memory")
#define WAITVM(N)  asm volatile("s_waitcnt vmcnt(" #N ")" ::: "memory")
#define WAITLGKM() asm volatile("s_waitcnt lgkmcnt(0)" ::: "memory")
#define BAR()      asm volatile("s_barrier" ::: "memory")
#define SCHEDBAR() __builtin_amdgcn_sched_barrier(0)

__global__ __launch_bounds__(256, 3) void k_gemm(const ull* __restrict__ Abits,
                                                 const unsigned short* __restrict__ Bsrc,
                                                 float* __restrict__ Cp) {
  __shared__ alignas(16) unsigned short Bs[3 * BSZ];     // 36 KB total LDS

  // bijective XCD swizzle: nwg = 768 (%8==0); nt fastest.
  int id  = blockIdx.x;
  int wg  = (id & 7) * (768 >> 3) + (id >> 3);
  int nt  = wg % NTILE;
  int mt  = (wg / NTILE) % MTILE;
  int ks  = wg / (NTILE * MTILE);

  int m0 = mt * BM, n0 = nt * BN, k0 = ks * (NT * BK);
  int tid = threadIdx.x;
  int lane = tid & 63, wid = tid >> 6;     // 4 waves, all-M: wave rows wid*32..+31
  f32x4 acc[2][6] = {};

  int hi = lane >> 4, r15 = lane & 15, x7 = lane & 7;
  int sh8 = hi * 8;

  // A-bit pointers: one uint64 per row per K-tile (64 bits = BK columns).
  const ull* A0 = Abits + (size_t)(m0 + wid * 32 + r15) * (NN / 64) + (k0 >> 6);
  const ull* A1 = A0 + (size_t)16 * (NN / 64);

  // B: global_load_lds with pre-swizzled source (3 chunks of 32 rows).
  int brow = tid >> 3, bgrp = tid & 7;
  const unsigned short* Bg = Bsrc + (size_t)(n0 + brow) * NN + k0
                           + (size_t)((bgrp ^ (brow & 7)) * 8);

  i32x2 ra[2];        // [m] — lo word = kk0 bits, hi word = kk1 bits

#define ALOAD(KT)                                                             \
  do { ra[0] = gload_i2(A0 + (KT)); ra[1] = gload_i2(A1 + (KT)); } while (0)

#define CONVERT()                                                             \
  do { _Pragma("unroll") for (int m = 0; m < 2; ++m) {                        \
    unsigned w0 = (unsigned)ra[m][0], w1 = (unsigned)ra[m][1];                \
    af[m][0] = expand8((w0 >> sh8) & 0xFFu);                                  \
    af[m][1] = expand8((w1 >> sh8) & 0xFFu);                                  \
  } } while (0)

#define BSTAGE(BIO, KO)                                                       \
  do { _Pragma("unroll") for (int r = 0; r < 3; ++r)                          \
    gload_lds16(Bg + (size_t)(r * 32) * NN + (KO),                            \
                &Bs[(unsigned)(BIO) + (unsigned)((r * 32 + wid * 8) * BK)]);  \
  } while (0)

#define COMPUTE(BCO)                                                          \
  do { _Pragma("unroll") for (int kk = 0; kk < 2; ++kk) {                     \
    bf16x8 bfr[6];                                                            \
    _Pragma("unroll") for (int n = 0; n < 6; ++n)                             \
      bfr[n] = *(const bf16x8*)&Bs[(unsigned)(BCO) +                          \
                                   (unsigned)((n * 16 + r15) * BK)            \
                                   + (unsigned)(((kk * 4 + hi) ^ x7) * 8)];   \
    _Pragma("unroll") for (int m = 0; m < 2; ++m)                             \
      _Pragma("unroll") for (int n = 0; n < 6; ++n)                           \
        acc[m][n] = __builtin_amdgcn_mfma_f32_16x16x32_bf16(af[m][kk], bfr[n],\
                                                            acc[m][n], 0,0,0);\
  } } while (0)

  bf16x8 af[2][2];

  // prologue: B(0)->buf0, A(0)->ra, B(1)->buf1   (queue: B0=3, A0=2, B1=3)
  BSTAGE(0, 0); SEP();
  ALOAD(0);     SEP();
  BSTAGE(BSZ, BK);

#pragma unroll
  for (int kt = 0; kt < NT; ++kt) {
    if (kt < NT - 1) { WAITVM(3); } else { WAITVM(0); }
    SCHEDBAR();                    // rule #18: pin CONVERT after the wait
    CONVERT();                     // ra -> af (VALU); ra dead after this
    SCHEDBAR();                    // pin next ALOAD below (no ra overlap)
    if (kt + 1 < NT) { ALOAD(kt + 1); SEP(); }
    WAITLGKM();                    // own ds_reads retired (race fix)
    BAR();                         // all waves done reading buf((kt+2)%3)
    if (kt + 2 < NT) BSTAGE((unsigned)(((kt + 2) % 3) * BSZ), (kt + 2) * BK);
    COMPUTE((unsigned)((kt % 3) * BSZ));
  }

  float* Cout = Cp + (size_t)ks * NN * NPAD;
#pragma unroll
  for (int m = 0; m < 2; ++m)
#pragma unroll
    for (int n = 0; n < 6; ++n)
#pragma unroll
      for (int j = 0; j < 4; ++j) {
        int row = m0 + wid * 32 + m * 16 + hi * 4 + j;
        int col = n0 + n * 16 + r15;
        Cout[(size_t)row * NPAD + col] = acc[m][n][j];
      }
#undef ALOAD
#undef CONVERT
#undef BSTAGE
#undef COMPUTE
}

// ---------------- epilogue: out[i,f] = (1/8) sum_h num/den over KS partials ----------------
__global__ __launch_bounds__(256) void k_epi(const float* __restrict__ Cp,
                                             float* __restrict__ out) {
  int idx = blockIdx.x * 256 + threadIdx.x;
  int i = idx >> 6, f = idx & 63;
  const float* row = Cp + (size_t)i * NPAD;
  const size_t stride = (size_t)NN * NPAD;
  float s = 0.f;
#pragma unroll
  for (int hh = 0; hh < NH; ++hh) {
    float num = 0.f, den = 0.f;
#pragma unroll
    for (int ks = 0; ks < KS; ++ks) {
      num += row[ks * stride + hh * HSTR + f];
      den += row[ks * stride + hh * HSTR + 64];
    }
    float inv = (den > 0.f) ? (1.f / den) : 0.f;
    s = fmaf(num, inv, s);
  }
  out[idx] = 0.125f * s;
}

extern "C" void kernel_launch(void* const* d_in, const int* in_sizes, int n_in,
                              void* d_out, int out_size, void* d_ws, size_t ws_size,
                              hipStream_t stream) {
  const float* feat = (const float*)d_in[0];
  const int*   adj  = (const int*)d_in[1];
  const float* W    = (const float*)d_in[2];
  const float* att  = (const float*)d_in[3];
  float* out = (float*)d_out;

  const size_t GT_B = (size_t)NPAD * NN * 2;         // 4.5 MB
  const size_t AB_B = (size_t)NN * (NN / 64) * 8;    // 2 MB
  char* ws = (char*)d_ws;
  unsigned short* Gt    = (unsigned short*)(ws);
  unsigned*       Ab32  = (unsigned*)(ws + GT_B);
  ull*            Abits = (ull*)(ws + GT_B);
  float*          Cp    = (float*)(ws + GT_B + AB_B); // KS x 9.4 MB partials

  k_pp  <<<PREP_BLOCKS + PACK_BLOCKS, 256, 0, stream>>>(adj, Ab32, feat, W, att, Gt);
  k_gemm<<<NTILE * MTILE * KS, 256, 0, stream>>>(Abits, Gt, Cp);
  k_epi <<<NN * OUTF / 256, 256, 0, stream>>>(Cp, out);
}

// Round 15
// 58.004 us; speedup vs baseline: 1.3723x; 1.0286x over previous
//
#include <hip/hip_runtime.h>
#include <hip/hip_bf16.h>

#define NN   4096
#define INF_ 256
#define OUTF 64
#define NH   8
#define HSTR 72
#define NPAD 576   // 8 heads * 72 (64 g + 1 e + 7 zero pad)

using bf16x8 = __attribute__((ext_vector_type(8))) short;
using f32x4  = __attribute__((ext_vector_type(4))) float;
using i32x2  = __attribute__((ext_vector_type(2))) int;
typedef unsigned long long ull;

__device__ __forceinline__ void gload_lds16(const void* g, void* l) {
  __builtin_amdgcn_global_load_lds((__attribute__((address_space(1))) void*)(g),
                                   (__attribute__((address_space(3))) void*)(l),
                                   16, 0, 0);
}

// compiler-invisible 8B global load (round-10/11 validated pattern).
__device__ __forceinline__ i32x2 gload_i2(const void* p) {
  i32x2 r;
  asm volatile("global_load_dwordx2 %0, %1, off" : "=v"(r) : "v"(p));
  return r;
}

__device__ __forceinline__ unsigned short f2bf(float x) {
  unsigned u = __float_as_uint(x);
  unsigned r = (u + 0x7FFFu + ((u >> 16) & 1u)) >> 16;
  return (unsigned short)r;
}

// 8 adjacency bits -> 8 bf16 {0.0, 1.0} packed as 4 uint32.
__device__ __forceinline__ bf16x8 expand8(unsigned b) {
  union { uint4 u; bf16x8 v; } cv;
  cv.u.x = ( b        & 1u) * 0x3F80u + ( b        & 2u) * 0x1FC00000u;
  cv.u.y = ((b >> 2)  & 1u) * 0x3F80u + ((b >> 2)  & 2u) * 0x1FC00000u;
  cv.u.z = ((b >> 4)  & 1u) * 0x3F80u + ((b >> 4)  & 2u) * 0x1FC00000u;
  cv.u.w = ((b >> 6)  & 1u) * 0x3F80u + ((b >> 6)  & 2u) * 0x1FC00000u;
  return cv.v;
}

// ---------------- fused prologue: prep (blocks 0..255) + pack (256..1279) ----
// Pack rewritten: DENSE dword loads + __ballot (4 independent chains/iter).
// Lane-local 32-col packing had 64 cache-lines per load instr (stride 128B);
// ballot over lane j = col j gives perfectly dense 256B loads, and the 16
// chunk iterations are independent (vs round-11's single serial chain).
#define PREP_BLOCKS (NN / 16)                // 256
#define PACK_BLOCKS (NN / 4)                 // 1024 (4 waves/block, 1 row/wave)

__global__ __launch_bounds__(256) void k_pp(const int* __restrict__ adj,
                                            ull* __restrict__ Abits,
                                            const float* __restrict__ feat,
                                            const float* __restrict__ W,
                                            const float* __restrict__ att,
                                            unsigned short* __restrict__ Gt) {
  __shared__ float fl[16][INF_];
  __shared__ float hl[16][65];
  __shared__ float el[NH][16];
  int tid = threadIdx.x;

  if (blockIdx.x >= PREP_BLOCKS) {
    // ---- bit-pack: bit j of word (row, c*4+q) = adj[row][c*256+q*64+j] > 0
    int lane = tid & 63, wave = tid >> 6;
    int row  = (blockIdx.x - PREP_BLOCKS) * 4 + wave;
    const int* src = adj + (size_t)row * NN + lane;
    ull* dst = Abits + (size_t)row * (NN / 64);
#pragma unroll 4
    for (int c = 0; c < NN / 256; ++c) {
      int b0 = src[c * 256];
      int b1 = src[c * 256 + 64];
      int b2 = src[c * 256 + 128];
      int b3 = src[c * 256 + 192];
      ull m0 = __ballot(b0 > 0);
      ull m1 = __ballot(b1 > 0);
      ull m2 = __ballot(b2 > 0);
      ull m3 = __ballot(b3 > 0);
      if (lane == 0) {
        dst[c * 4]     = m0;
        dst[c * 4 + 1] = m1;
        dst[c * 4 + 2] = m2;
        dst[c * 4 + 3] = m3;
      }
    }
    return;
  }

  // ---- prep: h = feat@W ; e = exp(h·a_dst) ; Gt build (16 rows/block)
  int j0 = blockIdx.x * 16;
  const float4* src = (const float4*)(feat + (size_t)j0 * INF_);
  for (int i = tid; i < 16 * 64; i += 256) {
    int r = i >> 6, c4 = i & 63;
    *(float4*)&fl[r][c4 * 4] = src[i];
  }
  __syncthreads();
  int c  = tid & 63;
  int rg = tid >> 6;
  float acc[4] = {0.f, 0.f, 0.f, 0.f};
#pragma unroll 8
  for (int k = 0; k < INF_; ++k) {
    float w = W[k * OUTF + c];
#pragma unroll
    for (int m = 0; m < 4; ++m) acc[m] = fmaf(fl[rg * 4 + m][k], w, acc[m]);
  }
#pragma unroll
  for (int m = 0; m < 4; ++m) hl[rg * 4 + m][c] = acc[m];
  __syncthreads();
  if (tid < NH * 16) {
    int hh = tid >> 4, row = tid & 15;
    float d = 0.f;
#pragma unroll 8
    for (int f = 0; f < 64; ++f) d = fmaf(hl[row][f], att[hh * 128 + 64 + f], d);
    el[hh][row] = expf(d);
  }
  __syncthreads();
  for (int i = tid; i < NPAD * 8; i += 256) {
    int u = i & 7, cc = i >> 3;
    int j2 = u * 2;
    int hh2 = cc / HSTR, c2 = cc - hh2 * HSTR;
    float e0 = el[hh2][j2], e1 = el[hh2][j2 + 1];
    float v0, v1;
    if (c2 < 64)      { v0 = e0 * hl[j2][c2]; v1 = e1 * hl[j2 + 1][c2]; }
    else if (c2 == 64){ v0 = e0;              v1 = e1; }
    else              { v0 = 0.f;             v1 = 0.f; }
    ushort2 o; o.x = f2bf(v0); o.y = f2bf(v1);
    *(ushort2*)&Gt[(size_t)cc * NN + j0 + j2] = o;
  }
}

// ---- Cp[ks] = A(bit-packed 0/1, expanded in-reg) @ Gt^T ----
// Round-11..14's validated structure (passed 4x), unchanged.
#define BM 128
#define BN 96
#define BK 64
#define KS 4
#define NT 16                 // (NN/KS)/BK
#define NTILE 6               // 576/96
#define MTILE 32
#define BSZ (BN * BK)         // 6144 ushorts = 12 KB per B buffer

#define SEP()      asm volatile("" ::: "memory")
#define WAITVM(N)  asm volatile("s_waitcnt vmcnt(" #N ")" ::: "memory")
#define WAITLGKM() asm volatile("s_waitcnt lgkmcnt(0)" ::: "memory")
#define BAR()      asm volatile("s_barrier" ::: "memory")
#define SCHEDBAR() __builtin_amdgcn_sched_barrier(0)

__global__ __launch_bounds__(256, 3) void k_gemm(const ull* __restrict__ Abits,
                                                 const unsigned short* __restrict__ Bsrc,
                                                 float* __restrict__ Cp) {
  __shared__ alignas(16) unsigned short Bs[3 * BSZ];     // 36 KB total LDS

  // bijective XCD swizzle: nwg = 768 (%8==0); nt fastest.
  int id  = blockIdx.x;
  int wg  = (id & 7) * (768 >> 3) + (id >> 3);
  int nt  = wg % NTILE;
  int mt  = (wg / NTILE) % MTILE;
  int ks  = wg / (NTILE * MTILE);

  int m0 = mt * BM, n0 = nt * BN, k0 = ks * (NT * BK);
  int tid = threadIdx.x;
  int lane = tid & 63, wid = tid >> 6;     // 4 waves, all-M: wave rows wid*32..+31
  f32x4 acc[2][6] = {};

  int hi = lane >> 4, r15 = lane & 15, x7 = lane & 7;
  int sh8 = hi * 8;

  // A-bit pointers: one uint64 per row per K-tile (64 bits = BK columns).
  const ull* A0 = Abits + (size_t)(m0 + wid * 32 + r15) * (NN / 64) + (k0 >> 6);
  const ull* A1 = A0 + (size_t)16 * (NN / 64);

  // B: global_load_lds with pre-swizzled source (3 chunks of 32 rows).
  int brow = tid >> 3, bgrp = tid & 7;
  const unsigned short* Bg = Bsrc + (size_t)(n0 + brow) * NN + k0
                           + (size_t)((bgrp ^ (brow & 7)) * 8);

  i32x2 ra[2];        // [m] — lo word = kk0 bits, hi word = kk1 bits

#define ALOAD(KT)                                                             \
  do { ra[0] = gload_i2(A0 + (KT)); ra[1] = gload_i2(A1 + (KT)); } while (0)

#define CONVERT()                                                             \
  do { _Pragma("unroll") for (int m = 0; m < 2; ++m) {                        \
    unsigned w0 = (unsigned)ra[m][0], w1 = (unsigned)ra[m][1];                \
    af[m][0] = expand8((w0 >> sh8) & 0xFFu);                                  \
    af[m][1] = expand8((w1 >> sh8) & 0xFFu);                                  \
  } } while (0)

#define BSTAGE(BIO, KO)                                                       \
  do { _Pragma("unroll") for (int r = 0; r < 3; ++r)                          \
    gload_lds16(Bg + (size_t)(r * 32) * NN + (KO),                            \
                &Bs[(unsigned)(BIO) + (unsigned)((r * 32 + wid * 8) * BK)]);  \
  } while (0)

#define COMPUTE(BCO)                                                          \
  do { _Pragma("unroll") for (int kk = 0; kk < 2; ++kk) {                     \
    bf16x8 bfr[6];                                                            \
    _Pragma("unroll") for (int n = 0; n < 6; ++n)                             \
      bfr[n] = *(const bf16x8*)&Bs[(unsigned)(BCO) +                          \
                                   (unsigned)((n * 16 + r15) * BK)            \
                                   + (unsigned)(((kk * 4 + hi) ^ x7) * 8)];   \
    _Pragma("unroll") for (int m = 0; m < 2; ++m)                             \
      _Pragma("unroll") for (int n = 0; n < 6; ++n)                           \
        acc[m][n] = __builtin_amdgcn_mfma_f32_16x16x32_bf16(af[m][kk], bfr[n],\
                                                            acc[m][n], 0,0,0);\
  } } while (0)

  bf16x8 af[2][2];

  // prologue: B(0)->buf0, A(0)->ra, B(1)->buf1   (queue: B0=3, A0=2, B1=3)
  BSTAGE(0, 0); SEP();
  ALOAD(0);     SEP();
  BSTAGE(BSZ, BK);

#pragma unroll
  for (int kt = 0; kt < NT; ++kt) {
    if (kt < NT - 1) { WAITVM(3); } else { WAITVM(0); }
    SCHEDBAR();                    // rule #18: pin CONVERT after the wait
    CONVERT();                     // ra -> af (VALU); ra dead after this
    SCHEDBAR();                    // pin next ALOAD below (no ra overlap)
    if (kt + 1 < NT) { ALOAD(kt + 1); SEP(); }
    WAITLGKM();                    // own ds_reads retired (race fix)
    BAR();                         // all waves done reading buf((kt+2)%3)
    if (kt + 2 < NT) BSTAGE((unsigned)(((kt + 2) % 3) * BSZ), (kt + 2) * BK);
    COMPUTE((unsigned)((kt % 3) * BSZ));
  }

  float* Cout = Cp + (size_t)ks * NN * NPAD;
#pragma unroll
  for (int m = 0; m < 2; ++m)
#pragma unroll
    for (int n = 0; n < 6; ++n)
#pragma unroll
      for (int j = 0; j < 4; ++j) {
        int row = m0 + wid * 32 + m * 16 + hi * 4 + j;
        int col = n0 + n * 16 + r15;
        Cout[(size_t)row * NPAD + col] = acc[m][n][j];
      }
#undef ALOAD
#undef CONVERT
#undef BSTAGE
#undef COMPUTE
}

// ---------------- epilogue: out[i,f] = (1/8) sum_h num/den over KS partials ----------------
__global__ __launch_bounds__(256) void k_epi(const float* __restrict__ Cp,
                                             float* __restrict__ out) {
  int idx = blockIdx.x * 256 + threadIdx.x;
  int i = idx >> 6, f = idx & 63;
  const float* row = Cp + (size_t)i * NPAD;
  const size_t stride = (size_t)NN * NPAD;
  float s = 0.f;
#pragma unroll
  for (int hh = 0; hh < NH; ++hh) {
    float num = 0.f, den = 0.f;
#pragma unroll
    for (int ks = 0; ks < KS; ++ks) {
      num += row[ks * stride + hh * HSTR + f];
      den += row[ks * stride + hh * HSTR + 64];
    }
    float inv = (den > 0.f) ? (1.f / den) : 0.f;
    s = fmaf(num, inv, s);
  }
  out[idx] = 0.125f * s;
}

extern "C" void kernel_launch(void* const* d_in, const int* in_sizes, int n_in,
                              void* d_out, int out_size, void* d_ws, size_t ws_size,
                              hipStream_t stream) {
  const float* feat = (const float*)d_in[0];
  const int*   adj  = (const int*)d_in[1];
  const float* W    = (const float*)d_in[2];
  const float* att  = (const float*)d_in[3];
  float* out = (float*)d_out;

  const size_t GT_B = (size_t)NPAD * NN * 2;         // 4.5 MB
  const size_t AB_B = (size_t)NN * (NN / 64) * 8;    // 2 MB
  char* ws = (char*)d_ws;
  unsigned short* Gt    = (unsigned short*)(ws);
  ull*            Abits = (ull*)(ws + GT_B);
  float*          Cp    = (float*)(ws + GT_B + AB_B); // KS x 9.4 MB partials

  k_pp  <<<PREP_BLOCKS + PACK_BLOCKS, 256, 0, stream>>>(adj, Abits, feat, W, att, Gt);
  k_gemm<<<NTILE * MTILE * KS, 256, 0, stream>>>(Abits, Gt, Cp);
  k_epi <<<NN * OUTF / 256, 256, 0, stream>>>(Cp, out);
}